// Round 1
// baseline (73.978 us; speedup 1.0000x reference)
//
#include <hip/hip_runtime.h>
#include <hip/hip_bf16.h>

// PolymorphicSNN: reference collapses to
//   out[:, :256]    = heaviside(x @ W_lin.T + b_lin - 1.0)
//   out[:, 256:8448] = 0    (spk_mode == 0 identically since reg_out in {0,1})
//
// B=8192, N=256, P=32, row stride = 256*(1+32) = 8448 f32.
// Write-BW bound: 277 MB/out per call.

#define SNN_B 8192
#define SNN_N 256
#define SNN_P 32
#define SNN_ROW (SNN_N * (SNN_P + 1))   // 8448 floats per output row
#define SNN_TB 8                        // batch rows per block

__global__ __launch_bounds__(256) void polysnn_kernel(
    const float* __restrict__ x,      // [B, N]
    const float* __restrict__ W,      // [N, N] row n = weights for output col n
    const float* __restrict__ bias,   // [N]
    float* __restrict__ out)          // [B, 8448]
{
    __shared__ float xs[SNN_TB][SNN_N];

    const int tid  = threadIdx.x;
    const int row0 = blockIdx.x * SNN_TB;

    // Stage 8 x-rows (8 KiB) into LDS: 2048 floats = 512 float4, 256 threads -> 2 each.
    {
        const float4* x4  = reinterpret_cast<const float4*>(x + (size_t)row0 * SNN_N);
        float4*       xs4 = reinterpret_cast<float4*>(&xs[0][0]);
        xs4[tid]       = x4[tid];
        xs4[tid + 256] = x4[tid + 256];
    }
    __syncthreads();

    // Thread n computes h[row0+r][n] for r = 0..7, accumulating in f64
    // (output is a hard threshold at h>1; f64 keeps us bit-stable vs the ref).
    const int n = tid;
    double acc[SNN_TB];
#pragma unroll
    for (int r = 0; r < SNN_TB; ++r) acc[r] = 0.0;

    const float4* w4 = reinterpret_cast<const float4*>(W + (size_t)n * SNN_N);
#pragma unroll 4
    for (int k4 = 0; k4 < SNN_N / 4; ++k4) {
        const float4 w = w4[k4];
        const int k = k4 * 4;
#pragma unroll
        for (int r = 0; r < SNN_TB; ++r) {
            // xs reads are wave-uniform -> LDS broadcast, conflict-free.
            acc[r] += (double)w.x * (double)xs[r][k + 0];
            acc[r] += (double)w.y * (double)xs[r][k + 1];
            acc[r] += (double)w.z * (double)xs[r][k + 2];
            acc[r] += (double)w.w * (double)xs[r][k + 3];
        }
    }

    const double bn = (double)bias[n];
#pragma unroll
    for (int r = 0; r < SNN_TB; ++r) {
        const double h = acc[r] + bn;
        out[(size_t)(row0 + r) * SNN_ROW + n] = (h > 1.0) ? 1.0f : 0.0f;
    }

    // Zero-fill the mixed region for our 8 rows: 8192 floats/row = 2048 float4.
    const float4 z = make_float4(0.f, 0.f, 0.f, 0.f);
#pragma unroll
    for (int r = 0; r < SNN_TB; ++r) {
        float4* o4 = reinterpret_cast<float4*>(out + (size_t)(row0 + r) * SNN_ROW + SNN_N);
#pragma unroll
        for (int i = 0; i < (SNN_ROW - SNN_N) / 4 / 256; ++i) {
            o4[tid + i * 256] = z;
        }
    }
}

extern "C" void kernel_launch(void* const* d_in, const int* in_sizes, int n_in,
                              void* d_out, int out_size, void* d_ws, size_t ws_size,
                              hipStream_t stream) {
    const float* x     = (const float*)d_in[0];
    const float* W_lin = (const float*)d_in[1];
    const float* b_lin = (const float*)d_in[2];
    // d_in[3] (W_sel) and d_in[4] (b_sel) are dead: spk_mode == 0 identically.
    float* out = (float*)d_out;

    dim3 grid(SNN_B / SNN_TB);   // 1024 blocks
    dim3 block(256);
    polysnn_kernel<<<grid, block, 0, stream>>>(x, W_lin, b_lin, out);
}

// Round 2
// 69.041 us; speedup vs baseline: 1.0715x; 1.0715x over previous
//
#include <hip/hip_runtime.h>
#include <hip/hip_bf16.h>

// PolymorphicSNN: reference collapses to
//   out[:, :256]     = heaviside(x @ W_lin.T + b_lin - 1.0)
//   out[:, 256:8448] = 0    (spk_mode == 0 identically since reg_out in {0,1},
//                            and scores is finite -> 256*0*scores == 0)
//
// B=8192, N=256, P=32, row stride = 256*33 = 8448 f32. Write-BW bound: 277 MB.
//
// Precision: accumulate f32; any |h-1| < 1e-3 is re-decided in f64
// (f32 worst-case accumulation error ~6e-5 << 1e-3, so the final decision is
// identical to the all-f64 kernel that passed with absmax 0).

#define SNN_B 8192
#define SNN_N 256
#define SNN_P 32
#define SNN_ROW (SNN_N * (SNN_P + 1))   // 8448 floats per output row
#define SNN_TB 8                        // batch rows per block

__global__ __launch_bounds__(256) void polysnn_kernel(
    const float* __restrict__ x,      // [B, N]
    const float* __restrict__ W,      // [N, N] row n = weights for output col n
    const float* __restrict__ bias,   // [N]
    float* __restrict__ out)          // [B, 8448]
{
    __shared__ float xs[SNN_TB][SNN_N];

    const int tid  = threadIdx.x;
    const int row0 = blockIdx.x * SNN_TB;

    // Stage 8 x-rows (8 KiB) into LDS: 2048 floats = 512 float4.
    {
        const float4* x4  = reinterpret_cast<const float4*>(x + (size_t)row0 * SNN_N);
        float4*       xs4 = reinterpret_cast<float4*>(&xs[0][0]);
        xs4[tid]       = x4[tid];
        xs4[tid + 256] = x4[tid + 256];
    }
    __syncthreads();

    // Zero-fill the mixed region first: pure store stream, no dependencies,
    // overlaps with the GEMM below across the 16 waves/CU.
    const float4 z = make_float4(0.f, 0.f, 0.f, 0.f);
#pragma unroll
    for (int r = 0; r < SNN_TB; ++r) {
        float4* o4 = reinterpret_cast<float4*>(out + (size_t)(row0 + r) * SNN_ROW + SNN_N);
#pragma unroll
        for (int i = 0; i < (SNN_ROW - SNN_N) / 4 / 256; ++i) {
            o4[tid + i * 256] = z;
        }
    }

    // f32 GEMM: thread n computes h[row0+r][n], r = 0..7.
    const int n = tid;
    float acc[SNN_TB];
#pragma unroll
    for (int r = 0; r < SNN_TB; ++r) acc[r] = 0.0f;

    const float4* w4  = reinterpret_cast<const float4*>(W + (size_t)n * SNN_N);
    const float4* xs4 = reinterpret_cast<const float4*>(&xs[0][0]);
#pragma unroll 8
    for (int k4 = 0; k4 < SNN_N / 4; ++k4) {
        const float4 w = w4[k4];
#pragma unroll
        for (int r = 0; r < SNN_TB; ++r) {
            // wave-uniform ds_read_b128 -> LDS broadcast, one instr / 4 floats
            const float4 xr = xs4[r * (SNN_N / 4) + k4];
            acc[r] = fmaf(w.x, xr.x, acc[r]);
            acc[r] = fmaf(w.y, xr.y, acc[r]);
            acc[r] = fmaf(w.z, xr.z, acc[r]);
            acc[r] = fmaf(w.w, xr.w, acc[r]);
        }
    }

    const float bn = bias[n];
#pragma unroll
    for (int r = 0; r < SNN_TB; ++r) {
        const float h = acc[r] + bn;
        float spike;
        if (__builtin_expect(fabsf(h - 1.0f) < 1e-3f, 0)) {
            // Borderline: re-decide in f64 (rare: ~1e-3 of all values).
            double a = (double)bn;
            const float* wr = W + (size_t)n * SNN_N;
            for (int k = 0; k < SNN_N; ++k)
                a += (double)wr[k] * (double)xs[r][k];
            spike = (a > 1.0) ? 1.0f : 0.0f;
        } else {
            spike = (h > 1.0f) ? 1.0f : 0.0f;
        }
        out[(size_t)(row0 + r) * SNN_ROW + n] = spike;
    }
}

extern "C" void kernel_launch(void* const* d_in, const int* in_sizes, int n_in,
                              void* d_out, int out_size, void* d_ws, size_t ws_size,
                              hipStream_t stream) {
    const float* x     = (const float*)d_in[0];
    const float* W_lin = (const float*)d_in[1];
    const float* b_lin = (const float*)d_in[2];
    // d_in[3] (W_sel) and d_in[4] (b_sel) are dead: spk_mode == 0 identically.
    float* out = (float*)d_out;

    dim3 grid(SNN_B / SNN_TB);   // 1024 blocks
    dim3 block(256);
    polysnn_kernel<<<grid, block, 0, stream>>>(x, W_lin, b_lin, out);
}